// Round 5
// baseline (179.524 us; speedup 1.0000x reference)
//
#include <hip/hip_runtime.h>
#include <hip/hip_bf16.h>

#define B_    4
#define N_    16384
#define D_    128
#define P_    100
#define BN_   65536      // B_*N_
#define PBN_  6553600    // P_*BN_
#define PPAD  112        // P padded to 7*16 MFMA p-tiles (k_proj)
#define KPAD  128        // P padded to 128 for k_comb's K dimension
#define NBIN  4096

typedef __attribute__((ext_vector_type(8))) short short8;   // 8 bf16 = 4 VGPR
typedef __attribute__((ext_vector_type(4))) float floatx4;  // MFMA C/D

// bf16 <-> f32 via raw bits (RNE; inputs are finite)
__device__ __forceinline__ unsigned short f2b(float f) {
    unsigned u = __float_as_uint(f);
    return (unsigned short)((u + 0x7FFFu + ((u >> 16) & 1u)) >> 16);
}
__device__ __forceinline__ float b2f(unsigned short h) {
    return __uint_as_float(((unsigned)h) << 16);
}
union S8U { short8 s; unsigned u[4]; };

// ---------------------------------------------------------------------------
// Kernel 1: theta normalization -> thb[p][d] (k_proj A-operand, rows>=100
// zero) and thbT[d][p] (k_comb B-operand, cols>=100 zero; NaN-safe K-pad).
// ---------------------------------------------------------------------------
__global__ void k_norm(const float* __restrict__ th,
                       unsigned short* __restrict__ thb,
                       unsigned short* __restrict__ thbT) {
    int p = blockIdx.x;       // 0..127
    int d = threadIdx.x;      // 0..127
    float v = 0.f;
    if (p < P_) v = th[p * D_ + d];
    float s = v * v;
    #pragma unroll
    for (int o = 32; o > 0; o >>= 1) s += __shfl_down(s, o, 64);
    __shared__ float red[2];
    if ((d & 63) == 0) red[d >> 6] = s;
    __syncthreads();
    float norm = fmaxf(sqrtf(red[0] + red[1]), 1e-12f);
    unsigned short r = f2b(v / norm);       // p>=100 -> +0
    if (p < PPAD) thb[p * D_ + d] = r;
    thbT[d * KPAD + p] = r;
}

// ---------------------------------------------------------------------------
// Kernel 2: projections via bf16 MFMA, ZERO input staging. B-frags (x,y) are
// direct global reads: per wave-instr 16 rows x 128B aligned segments (full
// cache lines). A-frags read thb straight from global (28KB, L1-resident —
// all blocks share it). LDS = one 16KB transpose buffer reused for x then y.
// No barrier before the MFMAs at all; VGPR ~120 -> 4 waves/EU (16 waves/CU,
// double R4's occupancy).
// ---------------------------------------------------------------------------
__global__ __launch_bounds__(256, 4) void k_proj(
    const float* __restrict__ x, const float* __restrict__ y,
    const unsigned short* __restrict__ thb,
    unsigned short* __restrict__ xp, unsigned short* __restrict__ yp) {
    __shared__ unsigned short buf[PPAD * 72];  // 16,128 B
    const int tid  = threadIdx.x;
    const int w    = tid >> 6;                // wave -> rows w*16..+15
    const int lane = tid & 63;
    const int n    = lane & 15;
    const int quad = lane >> 4;
    const int row0 = blockIdx.x * 64;

    // B-frags: row = row0 + w*16 + n, k = ks*32 + quad*8 .. +7 (fp32 -> bf16)
    short8 bx[4], by[4];
    const float* xr = x + (size_t)(row0 + w * 16 + n) * D_ + quad * 8;
    const float* yr = y + (size_t)(row0 + w * 16 + n) * D_ + quad * 8;
    #pragma unroll
    for (int ks = 0; ks < 4; ++ks) {
        float4 a = *(const float4*)(xr + ks * 32);
        float4 b = *(const float4*)(xr + ks * 32 + 4);
        float4 c = *(const float4*)(yr + ks * 32);
        float4 d = *(const float4*)(yr + ks * 32 + 4);
        S8U ux, uy;
        ux.u[0] = f2b(a.x) | ((unsigned)f2b(a.y) << 16);
        ux.u[1] = f2b(a.z) | ((unsigned)f2b(a.w) << 16);
        ux.u[2] = f2b(b.x) | ((unsigned)f2b(b.y) << 16);
        ux.u[3] = f2b(b.z) | ((unsigned)f2b(b.w) << 16);
        uy.u[0] = f2b(c.x) | ((unsigned)f2b(c.y) << 16);
        uy.u[1] = f2b(c.z) | ((unsigned)f2b(c.w) << 16);
        uy.u[2] = f2b(d.x) | ((unsigned)f2b(d.y) << 16);
        uy.u[3] = f2b(d.z) | ((unsigned)f2b(d.w) << 16);
        bx[ks] = ux.s; by[ks] = uy.s;
    }

    // MFMA: A direct from global thb (L1-hit after warmup)
    floatx4 accx[7], accy[7];
    #pragma unroll
    for (int pt = 0; pt < 7; ++pt) {
        accx[pt] = (floatx4){0.f, 0.f, 0.f, 0.f};
        accy[pt] = (floatx4){0.f, 0.f, 0.f, 0.f};
        const unsigned short* ar = thb + (size_t)(pt * 16 + n) * D_ + quad * 8;
        #pragma unroll
        for (int ks = 0; ks < 4; ++ks) {
            short8 a = *(const short8*)(ar + ks * 32);
            accx[pt] = __builtin_amdgcn_mfma_f32_16x16x32_bf16(a, bx[ks], accx[pt], 0, 0, 0);
            accy[pt] = __builtin_amdgcn_mfma_f32_16x16x32_bf16(a, by[ks], accy[pt], 0, 0, 0);
        }
    }

    // Epilogue: transpose x through buf, store; then y.
    #pragma unroll
    for (int pt = 0; pt < 7; ++pt)
        #pragma unroll
        for (int reg = 0; reg < 4; ++reg)
            buf[(pt * 16 + quad * 4 + reg) * 72 + w * 16 + n] = f2b(accx[pt][reg]);
    __syncthreads();
    for (int g = tid; g < 896; g += 256) {    // 112*64/8
        int p = g >> 3, c = (g & 7) << 3;
        *(uint4*)(xp + (size_t)p * BN_ + row0 + c) = *(const uint4*)(buf + p * 72 + c);
    }
    __syncthreads();
    #pragma unroll
    for (int pt = 0; pt < 7; ++pt)
        #pragma unroll
        for (int reg = 0; reg < 4; ++reg)
            buf[(pt * 16 + quad * 4 + reg) * 72 + w * 16 + n] = f2b(accy[pt][reg]);
    __syncthreads();
    for (int g = tid; g < 896; g += 256) {
        int p = g >> 3, c = (g & 7) << 3;
        *(uint4*)(yp + (size_t)p * BN_ + row0 + c) = *(const uint4*)(buf + p * 72 + c);
    }
}

// ---------------------------------------------------------------------------
// Kernel 3: fused counting sort + rank + diff, MERGED histogram phases.
// Both 4096-bin histograms counted in one pass (one returning atomic per
// element gives the intra-bin index), one merged scan (t0 scans y wave-sums,
// t1 scans x wave-sums in parallel), scatter-y + rank-x in the same phase.
// ~6 barriers vs R4's ~8, one scan serialization removed.
// LDS: 16K hy + 16K hx + 32K ysort = 64.1 KB, 2 blocks/CU (thread-capped).
// ---------------------------------------------------------------------------
__device__ __forceinline__ int binof(float v) {
    int k = (int)((v + 8.0f) * 256.0f);
    return k < 0 ? 0 : (k > NBIN - 1 ? NBIN - 1 : k);
}

__global__ __launch_bounds__(1024, 8) void k_sortdiff(
    const unsigned short* __restrict__ xp, const unsigned short* __restrict__ yp,
    unsigned short* __restrict__ diff) {
    __shared__ unsigned hy[NBIN], hx[NBIN];   // 32 KB
    __shared__ unsigned short ysort[N_];      // 32 KB
    __shared__ unsigned wsum[32];
    const size_t base = (size_t)blockIdx.x * N_ + (size_t)threadIdx.x * 16;
    const int t = threadIdx.x;
    const int lane = t & 63, w = t >> 6;

    unsigned yw[8], xw[8];
    {
        uint4 a = *(const uint4*)(yp + base), b = *(const uint4*)(yp + base + 8);
        yw[0]=a.x; yw[1]=a.y; yw[2]=a.z; yw[3]=a.w;
        yw[4]=b.x; yw[5]=b.y; yw[6]=b.z; yw[7]=b.w;
        uint4 c = *(const uint4*)(xp + base), d = *(const uint4*)(xp + base + 8);
        xw[0]=c.x; xw[1]=c.y; xw[2]=c.z; xw[3]=c.w;
        xw[4]=d.x; xw[5]=d.y; xw[6]=d.z; xw[7]=d.w;
    }
    #pragma unroll
    for (int i = 0; i < 4; ++i) { hy[t + i * 1024] = 0; hx[t + i * 1024] = 0; }
    __syncthreads();

    // ---- count both (returning atomics; j = intra-bin index) ----
    unsigned jy[8], jx[8];
    #pragma unroll
    for (int k = 0; k < 8; ++k) {
        unsigned a0 = atomicAdd(&hy[binof(b2f((unsigned short)(yw[k] & 0xffff)))], 1u);
        unsigned a1 = atomicAdd(&hy[binof(b2f((unsigned short)(yw[k] >> 16)))], 1u);
        jy[k] = a0 | (a1 << 16);
        unsigned c0 = atomicAdd(&hx[binof(b2f((unsigned short)(xw[k] & 0xffff)))], 1u);
        unsigned c1 = atomicAdd(&hx[binof(b2f((unsigned short)(xw[k] >> 16)))], 1u);
        jx[k] = c0 | (c1 << 16);
    }
    __syncthreads();

    // ---- merged exclusive scan of both histograms ----
    unsigned vy[4], vx[4], runy = 0, runx = 0;
    #pragma unroll
    for (int i = 0; i < 4; ++i) {
        unsigned a = hy[t * 4 + i], b = hx[t * 4 + i];
        vy[i] = runy; runy += a;
        vx[i] = runx; runx += b;
    }
    unsigned incy = runy, incx = runx;
    #pragma unroll
    for (int off = 1; off < 64; off <<= 1) {
        unsigned na = __shfl_up(incy, off, 64);
        unsigned nb = __shfl_up(incx, off, 64);
        if (lane >= off) { incy += na; incx += nb; }
    }
    if (lane == 63) { wsum[w] = incy; wsum[16 + w] = incx; }
    __syncthreads();
    if (t < 2) {                              // t0: y sums, t1: x sums (lockstep)
        unsigned r2 = 0;
        #pragma unroll
        for (int i = 0; i < 16; ++i) {
            unsigned h = wsum[t * 16 + i]; wsum[t * 16 + i] = r2; r2 += h;
        }
    }
    __syncthreads();
    unsigned basey = wsum[w] + (incy - runy);
    unsigned basex = wsum[16 + w] + (incx - runx);
    #pragma unroll
    for (int i = 0; i < 4; ++i) { hy[t * 4 + i] = basey + vy[i]; hx[t * 4 + i] = basex + vx[i]; }
    __syncthreads();

    // ---- scatter y into LDS + compute x ranks (same phase) ----
    unsigned rx[8];
    #pragma unroll
    for (int k = 0; k < 8; ++k) {
        unsigned short e0 = (unsigned short)(yw[k] & 0xffff);
        unsigned short e1 = (unsigned short)(yw[k] >> 16);
        ysort[hy[binof(b2f(e0))] + (jy[k] & 0xffff)] = e0;
        ysort[hy[binof(b2f(e1))] + (jy[k] >> 16)]    = e1;
        unsigned r0 = hx[binof(b2f((unsigned short)(xw[k] & 0xffff)))] + (jx[k] & 0xffff);
        unsigned r1 = hx[binof(b2f((unsigned short)(xw[k] >> 16)))]    + (jx[k] >> 16);
        rx[k] = r0 | (r1 << 16);
    }
    __syncthreads();

    // ---- gather + diff store ----
    unsigned ow[8];
    #pragma unroll
    for (int k = 0; k < 8; ++k) {
        float x0 = b2f((unsigned short)(xw[k] & 0xffff));
        float x1 = b2f((unsigned short)(xw[k] >> 16));
        unsigned short d0 = f2b(b2f(ysort[rx[k] & 0xffff]) - x0);
        unsigned short d1 = f2b(b2f(ysort[rx[k] >> 16])    - x1);
        ow[k] = (unsigned)d0 | ((unsigned)d1 << 16);
    }
    *(uint4*)(diff + base)     = make_uint4(ow[0], ow[1], ow[2], ow[3]);
    *(uint4*)(diff + base + 8) = make_uint4(ow[4], ow[5], ow[6], ow[7]);
}

// ---------------------------------------------------------------------------
// Kernel 4: combine via bf16 MFMA with FUSED transpose (k_trans absorbed).
// diff[p][row] tiles pair-packed into LDS [k2][row] dwords; the (lo=even k,
// hi=odd k) dword order IS the short8 A-frag bit layout, so A-frags are
// 4x ds_read_b32 (2-way bank aliasing only = free). B = thbT direct from
// global (32KB, L1/L2-resident). Saves the 30MB diffT round trip + a launch.
// ---------------------------------------------------------------------------
__global__ __launch_bounds__(256, 4) void k_comb(
    const float* __restrict__ x, const unsigned short* __restrict__ diff,
    const unsigned short* __restrict__ thbT, float* __restrict__ out) {
    __shared__ unsigned Lp[64 * 68];          // [k2][row], 17,408 B
    const int tid  = threadIdx.x;
    const int w    = tid >> 6;
    const int lane = tid & 63;
    const int n16  = lane & 15;
    const int quad = lane >> 4;
    const int row0 = blockIdx.x * 64;

    for (int g = tid; g < 952; g += 256) Lp[50 * 68 + g] = 0;   // K-pad zeros
    for (int g = tid; g < 400; g += 256) {
        int p2 = g >> 3, rg = (g & 7) << 3;
        uint4 a = *(const uint4*)(diff + (size_t)(2 * p2) * BN_ + row0 + rg);
        uint4 b = *(const uint4*)(diff + (size_t)(2 * p2 + 1) * BN_ + row0 + rg);
        unsigned* dst = Lp + p2 * 68 + rg;
        dst[0] = (a.x & 0xffffu) | (b.x << 16);
        dst[1] = (a.x >> 16)     | (b.x & 0xffff0000u);
        dst[2] = (a.y & 0xffffu) | (b.y << 16);
        dst[3] = (a.y >> 16)     | (b.y & 0xffff0000u);
        dst[4] = (a.z & 0xffffu) | (b.z << 16);
        dst[5] = (a.z >> 16)     | (b.z & 0xffff0000u);
        dst[6] = (a.w & 0xffffu) | (b.w << 16);
        dst[7] = (a.w >> 16)     | (b.w & 0xffff0000u);
    }
    __syncthreads();

    // A-frags: row m = w*16+n16, k = ks*32 + quad*8 .. +7  ->  4 dwords at
    // k2 = ks*16 + quad*4 + i  (pair packing matches short8 element order)
    S8U af[4];
    #pragma unroll
    for (int ks = 0; ks < 4; ++ks)
        #pragma unroll
        for (int i = 0; i < 4; ++i)
            af[ks].u[i] = Lp[(ks * 16 + quad * 4 + i) * 68 + w * 16 + n16];

    floatx4 acc[8];
    #pragma unroll
    for (int nt = 0; nt < 8; ++nt) {
        acc[nt] = (floatx4){0.f, 0.f, 0.f, 0.f};
        const unsigned short* br = thbT + (size_t)(nt * 16 + n16) * KPAD + quad * 8;
        #pragma unroll
        for (int ks = 0; ks < 4; ++ks) {
            short8 b = *(const short8*)(br + ks * 32);
            acc[nt] = __builtin_amdgcn_mfma_f32_16x16x32_bf16(af[ks].s, b, acc[nt], 0, 0, 0);
        }
    }

    const float invP = 1.0f / (float)P_;
    const size_t rbase = (size_t)(row0 + w * 16 + quad * 4) * D_ + n16;
    #pragma unroll
    for (int nt = 0; nt < 8; ++nt)
        #pragma unroll
        for (int reg = 0; reg < 4; ++reg) {
            size_t o = rbase + (size_t)reg * D_ + nt * 16;
            out[o] = fmaf(acc[nt][reg], invP, x[o]);
        }
}

// ---------------------------------------------------------------------------
// Workspace (bytes): thb[0,32K) thbT[32K,64K) xp[64K,+13.1MB) yp(+13.1MB)
// => 26.3 MB. diff overwrites xp in place.
// ---------------------------------------------------------------------------
extern "C" void kernel_launch(void* const* d_in, const int* in_sizes, int n_in,
                              void* d_out, int out_size, void* d_ws, size_t ws_size,
                              hipStream_t stream) {
    const float* x  = (const float*)d_in[0];
    const float* y  = (const float*)d_in[1];
    const float* th = (const float*)d_in[2];
    float* out = (float*)d_out;
    char*  wsb = (char*)d_ws;

    unsigned short* thb  = (unsigned short*)wsb;
    unsigned short* thbT = (unsigned short*)(wsb + 32768);
    unsigned short* xpb  = (unsigned short*)(wsb + 65536);
    unsigned short* ypb  = xpb + PBN_;

    k_norm<<<128, 128, 0, stream>>>(th, thb, thbT);
    k_proj<<<BN_ / 64, 256, 0, stream>>>(x, y, thb, xpb, ypb);
    k_sortdiff<<<P_ * B_, 1024, 0, stream>>>(xpb, ypb, xpb);
    k_comb<<<BN_ / 64, 256, 0, stream>>>(x, xpb, thbT, out);
}